// Round 2
// baseline (9107.561 us; speedup 1.0000x reference)
//
#include <hip/hip_runtime.h>
#include <math.h>

#define T_ 1024
#define D_ 512
#define NT_ 4096
#define MASKSELF -50000.0

// ---------------- embedding (fp64): circular conv1d + mark proj + pos emb ----------------
__global__ __launch_bounds__(256)
void embed_kernel(const float* __restrict__ x_enc, const float* __restrict__ x_mark_enc,
                  const float* __restrict__ x_dec, const float* __restrict__ x_mark_dec,
                  const float* __restrict__ conv_w, const float* __restrict__ mark_w,
                  double* __restrict__ h) {
  int bt = blockIdx.x;
  int b = bt >> 10, t = bt & 1023;
  __shared__ double xs[3][7];
  __shared__ double xm[4];
  int tid = threadIdx.x;
  if (tid < 21) {
    int k = tid / 7, i = tid % 7;
    int tt = t + k - 1;
    if (tt < 0) tt += 1024;
    if (tt >= 1024) tt -= 1024;
    xs[k][i] = (double)((tt < 768) ? x_enc[((size_t)b*768 + tt)*7 + i]
                                   : x_dec[((size_t)b*512 + (tt - 512))*7 + i]);
  }
  if (tid >= 32 && tid < 36) {
    int m = tid - 32;
    xm[m] = (double)((t < 768) ? x_mark_enc[((size_t)b*768 + t)*4 + m]
                               : x_mark_dec[((size_t)b*512 + (t - 512))*4 + m]);
  }
  __syncthreads();
  for (int o = tid; o < 512; o += 256) {
    double acc = 0.0;
    #pragma unroll
    for (int k = 0; k < 3; ++k)
      #pragma unroll
      for (int i = 0; i < 7; ++i)
        acc += xs[k][i] * (double)conv_w[(o*7 + i)*3 + k];
    #pragma unroll
    for (int m = 0; m < 4; ++m) acc += xm[m] * (double)mark_w[m*512 + o];
    int j2 = o & ~1;
    double dv = exp((double)j2 * (-9.210340371976184 / 512.0));
    double arg = (double)t * dv;
    acc += (o & 1) ? cos(arg) : sin(arg);
    h[((size_t)b*1024 + t)*512 + o] = acc;
  }
}

// ---------------- fp64 tiled GEMM 64x64x16, 256 thr, 4x4 microtile ----------------
// A: f64 [M,K]; Bm: f32 [K,N] (cast); flags: 1=+bias, 2=gelu(exact), 4=qkv layout
__global__ __launch_bounds__(256)
void dgemm_kernel(const double* __restrict__ A, const float* __restrict__ Bm,
                  const float* __restrict__ bias, double* __restrict__ C,
                  int N, int K, int flags) {
  __shared__ double As[16][64];
  __shared__ double Bs[16][66];
  int tid = threadIdx.x;
  int tx = tid & 15, ty = tid >> 4;
  int arow = blockIdx.x * 64;
  int bcol = blockIdx.y * 64;
  double acc[4][4];
  #pragma unroll
  for (int i=0;i<4;++i)
    #pragma unroll
    for (int j=0;j<4;++j) acc[i][j]=0.0;
  for (int k0 = 0; k0 < K; k0 += 16) {
    #pragma unroll
    for (int q = 0; q < 2; ++q) {
      int e = tid*2 + q;
      int r = e >> 3, c2 = (e & 7)*2;
      double2 av = *(const double2*)(A + (size_t)(arow + r)*K + k0 + c2);
      As[c2][r] = av.x; As[c2+1][r] = av.y;
      int kk = e >> 5, cc = (e & 31)*2;
      float2 bv = *(const float2*)(Bm + (size_t)(k0+kk)*N + bcol + cc);
      Bs[kk][cc] = (double)bv.x; Bs[kk][cc+1] = (double)bv.y;
    }
    __syncthreads();
    #pragma unroll
    for (int kk=0;kk<16;++kk) {
      double a[4], bb[4];
      #pragma unroll
      for (int i=0;i<4;++i) a[i] = As[kk][ty*4+i];
      #pragma unroll
      for (int j=0;j<4;++j) bb[j] = Bs[kk][tx*4+j];
      #pragma unroll
      for (int i=0;i<4;++i)
        #pragma unroll
        for (int j=0;j<4;++j) acc[i][j] += a[i]*bb[j];
    }
    __syncthreads();
  }
  #pragma unroll
  for (int i=0;i<4;++i) {
    int row = arow + ty*4 + i;
    #pragma unroll
    for (int j=0;j<4;++j) {
      int col = bcol + tx*4 + j;
      double cv = acc[i][j];
      if (flags & 1) cv += (double)bias[col];
      if (flags & 2) cv = 0.5*cv*(1.0 + erf(cv*0.70710678118654752440));
      if (flags & 4) {
        int b = row >> 10, t = row & 1023;
        int hd = col >> 6, dd = col & 63;
        C[(((size_t)b*8 + hd)*1024 + t)*64 + dd] = cv;
      } else {
        C[(size_t)row*N + col] = cv;
      }
    }
  }
}

// ---------------- LSH bucket assignment + per-round counting sort (fp64) ----------------
__global__ __launch_bounds__(256)
void bucket_sort_kernel(const double* __restrict__ qk, const float* __restrict__ rot,
                        int* __restrict__ sticker) {
  int bh = blockIdx.x >> 2, r = blockIdx.x & 3;
  __shared__ double rots[64][17];
  __shared__ unsigned char bucket[1024];
  __shared__ int cnt[32];
  __shared__ int off[32];
  int tid = threadIdx.x;
  for (int idx = tid; idx < 1024; idx += 256) {
    int f = idx >> 4, i = idx & 15;
    rots[f][i] = (double)rot[(f*4 + r)*16 + i];
  }
  if (tid < 32) cnt[tid] = 0;
  __syncthreads();
  for (int t = tid; t < 1024; t += 256) {
    const double* q = qk + ((size_t)bh*1024 + t)*64;
    double rv[16];
    #pragma unroll
    for (int i=0;i<16;++i) rv[i]=0.0;
    for (int f=0; f<64; ++f) {
      double qf = q[f];
      #pragma unroll
      for (int i=0;i<16;++i) rv[i] += qf * rots[f][i];
    }
    int best = 0; double bv = rv[0];
    #pragma unroll
    for (int i=1;i<16;++i) if (rv[i] > bv) { bv=rv[i]; best=i; }
    #pragma unroll
    for (int i=0;i<16;++i) { double nv = -rv[i]; if (nv > bv) { bv=nv; best=16+i; } }
    bucket[t] = (unsigned char)best;
    atomicAdd(&cnt[best], 1);
  }
  __syncthreads();
  if (tid == 0) {
    int s = 0;
    for (int k=0;k<32;++k) { off[k]=s; s+=cnt[k]; }
  }
  __syncthreads();
  if (tid < 32) {                 // stable placement
    int pos = off[tid];
    int* outp = sticker + (size_t)bh*NT_ + r*1024;
    for (int t=0;t<1024;++t)
      if (bucket[t] == (unsigned char)tid) outp[pos++] = t;
  }
}

// ---------------- chunked LSH attention fp64 (32 q x 64 kv), two-phase LDS ----------------
__global__ __launch_bounds__(256)
void lsh_attn_kernel(const double* __restrict__ qk, const double* __restrict__ v,
                     const int* __restrict__ sticker,
                     double* __restrict__ obuf, double* __restrict__ lse, int bh0) {
  int bh_l = blockIdx.x >> 7;
  int bh = bh0 + bh_l;
  int c  = blockIdx.x & 127;
  int cprev = (c + 127) & 127;
  __shared__ double kv[64][66];
  __shared__ double pp[32][66];
  __shared__ double rnorm[64];
  __shared__ int tk[64];
  int tid = threadIdx.x;
  if (tid < 64) {
    int chunk = (tid < 32) ? c : cprev;
    tk[tid] = sticker[(size_t)bh*NT_ + chunk*32 + (tid & 31)];
  }
  __syncthreads();
  for (int idx = tid; idx < 2048; idx += 256) {   // load K (both chunks)
    int j = idx >> 5, c2 = (idx & 31)*2;
    *(double2*)&kv[j][c2] = *(const double2*)(qk + ((size_t)bh*1024 + tk[j])*64 + c2);
  }
  __syncthreads();
  if (tid < 64) {
    double s = 0.0;
    #pragma unroll
    for (int f=0; f<64; ++f) { double x = kv[tid][f]; s += x*x; }
    rnorm[tid] = 1.0 / fmax(sqrt(s), 1e-12);
  }
  __syncthreads();
  int i = tid >> 3, sub = tid & 7;
  int ti = tk[i];
  double dots[8];
  double dmax = -1.0e300;
  #pragma unroll
  for (int jj=0; jj<8; ++jj) {
    int j = sub*8 + jj;
    double s = 0.0;
    #pragma unroll
    for (int f=0; f<64; ++f) s += kv[i][f] * kv[j][f];
    s *= rnorm[j] * 0.125;
    if (ti == tk[j]) s = MASKSELF;
    dots[jj] = s;
    dmax = fmax(dmax, s);
  }
  #pragma unroll
  for (int w=1; w<8; w<<=1) dmax = fmax(dmax, __shfl_xor(dmax, w, 64));
  double esum = 0.0;
  #pragma unroll
  for (int jj=0; jj<8; ++jj) {
    double e = exp(dots[jj] - dmax);
    esum += e;
    pp[i][sub*8+jj] = e;
  }
  #pragma unroll
  for (int w=1; w<8; w<<=1) esum += __shfl_xor(esum, w, 64);
  __syncthreads();
  for (int idx = tid; idx < 2048; idx += 256) {   // load V over K
    int j = idx >> 5, c2 = (idx & 31)*2;
    *(double2*)&kv[j][c2] = *(const double2*)(v + ((size_t)bh*1024 + tk[j])*64 + c2);
  }
  __syncthreads();
  double ov[8];
  #pragma unroll
  for (int dd=0;dd<8;++dd) ov[dd]=0.0;
  for (int j=0;j<64;++j) {
    double p = pp[i][j];
    #pragma unroll
    for (int dd=0;dd<8;++dd) ov[dd] += p * kv[j][sub*8+dd];
  }
  double rinv = 1.0 / esum;
  int r = c >> 5;
  size_t ob = (((size_t)bh_l*4 + r)*1024 + ti)*64 + sub*8;
  #pragma unroll
  for (int dd=0;dd<8;++dd) obuf[ob + dd] = ov[dd]*rinv;
  if (sub == 0) lse[((size_t)bh*4 + r)*1024 + ti] = log(esum) + dmax;
}

// ---------------- combine rounds (fp64) ----------------
__global__ __launch_bounds__(256)
void combine_kernel(const double* __restrict__ obuf, const double* __restrict__ lse,
                    double* __restrict__ comb, int bh0) {
  int g = blockIdx.x*4 + (threadIdx.x >> 6);      // 0..16383 over (bh_l, t)
  int bh_l = g >> 10, t = g & 1023;
  int bh = bh0 + bh_l;
  int d = threadIdx.x & 63;
  double l[4];
  #pragma unroll
  for (int r=0;r<4;++r) l[r] = lse[((size_t)bh*4 + r)*1024 + t];
  double m = fmax(fmax(l[0],l[1]), fmax(l[2],l[3]));
  double e[4], s=0.0;
  #pragma unroll
  for (int r=0;r<4;++r){ e[r]=exp(l[r]-m); s+=e[r]; }
  double rs = 1.0/s;
  double o = 0.0;
  #pragma unroll
  for (int r=0;r<4;++r)
    o += e[r]*rs * obuf[(((size_t)bh_l*4 + r)*1024 + t)*64 + d];
  int b = bh >> 3, hd = bh & 7;
  comb[((size_t)b*1024 + t)*512 + hd*64 + d] = o;
}

// ---------------- layernorm fp64 (optional residual add) ----------------
__global__ __launch_bounds__(256)
void ln_kernel(const double* __restrict__ x, const double* __restrict__ res,
               const float* __restrict__ gw, const float* __restrict__ bw,
               double* __restrict__ outp) {
  int row = blockIdx.x;
  int tid = threadIdx.x;
  const double* xr = x + (size_t)row*512;
  double v0 = xr[tid], v1 = xr[tid+256];
  if (res) { const double* rr = res + (size_t)row*512; v0 += rr[tid]; v1 += rr[tid+256]; }
  double s = v0 + v1;
  #pragma unroll
  for (int w=1; w<64; w<<=1) s += __shfl_xor(s, w, 64);
  __shared__ double red[4];
  int wid = tid >> 6, lane = tid & 63;
  if (lane == 0) red[wid] = s;
  __syncthreads();
  s = red[0]+red[1]+red[2]+red[3];
  double m = s * (1.0/512.0);
  double d0 = v0 - m, d1 = v1 - m;
  double q = d0*d0 + d1*d1;
  #pragma unroll
  for (int w=1; w<64; w<<=1) q += __shfl_xor(q, w, 64);
  __syncthreads();
  if (lane == 0) red[wid] = q;
  __syncthreads();
  q = red[0]+red[1]+red[2]+red[3];
  double var = q * (1.0/512.0);
  double rstd = 1.0 / sqrt(var + 1e-5);
  outp[(size_t)row*512 + tid]       = d0*rstd*(double)gw[tid] + (double)bw[tid];
  outp[(size_t)row*512 + tid + 256] = d1*rstd*(double)gw[tid+256] + (double)bw[tid+256];
}

// ---------------- final projection (fp64 accum, f32 store) ----------------
__global__ __launch_bounds__(64)
void proj_kernel(const double* __restrict__ hf, const float* __restrict__ pw,
                 const float* __restrict__ pb, float* __restrict__ outp) {
  int row = blockIdx.x;                       // 0..B*PRED-1
  int b = row >> 8, tp = row & 255;
  const double* hr = hf + ((size_t)b*1024 + 768 + tp)*512;
  int lane = threadIdx.x;
  double acc[7];
  #pragma unroll
  for (int cc=0;cc<7;++cc) acc[cc]=0.0;
  for (int d = lane; d < 512; d += 64) {
    double hv = hr[d];
    #pragma unroll
    for (int cc=0;cc<7;++cc) acc[cc] += hv * (double)pw[d*7 + cc];
  }
  #pragma unroll
  for (int cc=0;cc<7;++cc) {
    double s = acc[cc];
    #pragma unroll
    for (int w=32;w>=1;w>>=1) s += __shfl_xor(s, w, 64);
    if (lane == 0) outp[(size_t)row*7 + cc] = (float)(s + (double)pb[cc]);
  }
}

extern "C" void kernel_launch(void* const* d_in, const int* in_sizes, int n_in,
                              void* d_out, int out_size, void* d_ws, size_t ws_size,
                              hipStream_t stream) {
  (void)in_sizes; (void)n_in; (void)out_size; (void)ws_size;
  const float* x_enc      = (const float*)d_in[0];
  const float* x_mark_enc = (const float*)d_in[1];
  const float* x_dec      = (const float*)d_in[2];
  const float* x_mark_dec = (const float*)d_in[3];
  const float* conv_w     = (const float*)d_in[4];
  const float* mark_w     = (const float*)d_in[5];
  const float* qk_w       = (const float*)d_in[6];
  const float* v_w        = (const float*)d_in[7];
  const float* out_w      = (const float*)d_in[8];
  const float* out_b      = (const float*)d_in[9];
  const float* ln1_g      = (const float*)d_in[10];
  const float* ln1_b      = (const float*)d_in[11];
  const float* ln2_g      = (const float*)d_in[12];
  const float* ln2_b      = (const float*)d_in[13];
  const float* ffn_w1     = (const float*)d_in[14];
  const float* ffn_b1     = (const float*)d_in[15];
  const float* ffn_w2     = (const float*)d_in[16];
  const float* ffn_b2     = (const float*)d_in[17];
  const float* lnf_g      = (const float*)d_in[18];
  const float* lnf_b      = (const float*)d_in[19];
  const float* proj_w     = (const float*)d_in[20];
  const float* proj_b     = (const float*)d_in[21];
  const float* rotations  = (const float*)d_in[22];

  char* ws = (char*)d_ws;
  double* h64  = (double*)(ws);                  //  64 MB [16384][512]
  double* qk64 = (double*)(ws + 67108864);       //  64 MB [128][1024][64] / scratch
  double* v64  = (double*)(ws + 134217728);      //  64 MB [128][1024][64]  (== comb [16384][512])
  double* obuf = (double*)(ws + 201326592);      //  32 MB 16-bh o_rounds / 2048-row ffn hidden
  int*    stick= (int*)   (ws + 234881024);      //   2 MB
  double* lse  = (double*)(ws + 236978176);      //   4 MB   (total 230 MB)
  double* comb = v64;

  embed_kernel<<<16384, 256, 0, stream>>>(x_enc, x_mark_enc, x_dec, x_mark_dec,
                                          conv_w, mark_w, h64);
  for (int l = 0; l < 2; ++l) {
    dgemm_kernel<<<dim3(256,8), 256, 0, stream>>>(h64, qk_w + (size_t)l*512*512, nullptr,
                                                  qk64, 512, 512, 4);
    dgemm_kernel<<<dim3(256,8), 256, 0, stream>>>(h64, v_w + (size_t)l*512*512, nullptr,
                                                  v64, 512, 512, 4);
    bucket_sort_kernel<<<512, 256, 0, stream>>>(qk64, rotations + (size_t)l*64*4*16, stick);
    for (int g = 0; g < 8; ++g) {
      lsh_attn_kernel<<<2048, 256, 0, stream>>>(qk64, v64, stick, obuf, lse, g*16);
      combine_kernel<<<4096, 256, 0, stream>>>(obuf, lse, comb, g*16);
    }
    dgemm_kernel<<<dim3(256,8), 256, 0, stream>>>(comb, out_w + (size_t)l*512*512,
                                                  out_b + (size_t)l*512, qk64, 512, 512, 1);
    ln_kernel<<<16384, 256, 0, stream>>>(h64, qk64, ln1_g + l*512, ln1_b + l*512, h64);
    for (int c = 0; c < 8; ++c) {
      dgemm_kernel<<<dim3(32,32), 256, 0, stream>>>(h64 + (size_t)c*2048*512,
                                                    ffn_w1 + (size_t)l*512*2048,
                                                    ffn_b1 + (size_t)l*2048, obuf, 2048, 512, 3);
      dgemm_kernel<<<dim3(32,8), 256, 0, stream>>>(obuf, ffn_w2 + (size_t)l*2048*512,
                                                   ffn_b2 + (size_t)l*512,
                                                   comb + (size_t)c*2048*512, 512, 2048, 1);
    }
    ln_kernel<<<16384, 256, 0, stream>>>(h64, comb, ln2_g + l*512, ln2_b + l*512, h64);
  }
  ln_kernel<<<16384, 256, 0, stream>>>(h64, nullptr, lnf_g, lnf_b, qk64);
  proj_kernel<<<4096, 64, 0, stream>>>(qk64, proj_w, proj_b, (float*)d_out);
}